// Round 1
// 1104.700 us; speedup vs baseline: 1.0010x; 1.0010x over previous
//
#include <hip/hip_runtime.h>
#include <hip/hip_bf16.h>

typedef __attribute__((ext_vector_type(8))) short short8;
typedef __attribute__((ext_vector_type(4))) float f32x4;

// Problem constants
constexpr int B_ = 64, C_ = 256, H_ = 100, W_ = 152;
constexpr int K_ = C_ * 49;            // 12544
constexpr int R_ = 1024;               // rep
constexpr int KB_ = K_ / 32;           // 392 chunks of k=32
constexpr int KG_ = 32;                // split-K groups
constexpr float SCALE_ = 0.0625f;

// fp32 -> bf16 bits, round-to-nearest-even (inputs are finite/normal)
__device__ __forceinline__ short f2bf(float f) {
    unsigned u = __builtin_bit_cast(unsigned, f);
    u += 0x7FFFu + ((u >> 16) & 1u);
    return (short)(u >> 16);
}

// ---------------------------------------------------------------------------
// Kernel 1: RoIAlign -> featT (bf16) in MFMA A-fragment order:
//   featT[(kb*64 + b)*32 + (k & 31)] = feat[b][k],  kb = k>>5, k = c*49+py*7+px
// Exactly 49 blocks per image -> b (and all bbox math) is block-uniform (SGPR).
// All 16 bilinear corner loads are issued UNGUARDED (clamped coords are always
// in-bounds); validity is folded into the weights.  MLP 4 -> 16.
// ---------------------------------------------------------------------------
__global__ __launch_bounds__(256) void roi_kernel(const float* __restrict__ x,
                                                  const float* __restrict__ bbox,
                                                  short* __restrict__ featT) {
    int blk = blockIdx.x;
    int b   = blk / 49;                       // uniform per block
    int t   = (blk - b * 49) * 256 + threadIdx.x;  // elem within image, 0..12543
    int c   = t / 49;
    int bin = t - c * 49;
    int py  = bin / 7;
    int px  = bin - py * 7;

    const float* bb = bbox + b * 4;
    // boxes_xyxy = bbox[:, [0,2,1,3]] -> x1=bb[0], y1=bb[2], x2=bb[1], y2=bb[3]
    float x1 = bb[0] * SCALE_;
    float x2 = bb[1] * SCALE_;
    float y1 = bb[2] * SCALE_;
    float y2 = bb[3] * SCALE_;
    float bin_w = fmaxf(x2 - x1, 1.0f) * (1.0f / 7.0f);
    float bin_h = fmaxf(y2 - y1, 1.0f) * (1.0f / 7.0f);

    const float* fplane = x + (size_t)(b * C_ + c) * (H_ * W_);

    // Per-axis sample indices and validity-weighted bilinear weights.
    int   ro[2][2];    // [sy][iy]: row byte-offsets (in floats)
    float wy[2][2];    // [sy][iy]: hy/ly, zeroed when sample invalid
    int   xo[2][2];    // [sx][ix]: column indices
    float wx[2][2];    // [sx][ix]: hx/lx, zeroed when sample invalid

#pragma unroll
    for (int sy = 0; sy < 2; ++sy) {
        float ysf = y1 + ((float)py + ((float)sy + 0.5f) * 0.5f) * bin_h;
        float vy  = (ysf >= -1.0f && ysf <= (float)H_) ? 1.0f : 0.0f;
        float yc  = fminf(fmaxf(ysf, 0.0f), (float)(H_ - 1));
        int   y0  = (int)yc;                  // yc >= 0 -> trunc == floor
        int   y1i = min(y0 + 1, H_ - 1);
        float ly  = yc - (float)y0;
        ro[sy][0] = y0 * W_;
        ro[sy][1] = y1i * W_;
        wy[sy][0] = (1.0f - ly) * vy;
        wy[sy][1] = ly * vy;
    }
#pragma unroll
    for (int sx = 0; sx < 2; ++sx) {
        float xsf = x1 + ((float)px + ((float)sx + 0.5f) * 0.5f) * bin_w;
        float vx  = (xsf >= -1.0f && xsf <= (float)W_) ? 1.0f : 0.0f;
        float xc  = fminf(fmaxf(xsf, 0.0f), (float)(W_ - 1));
        int   x0  = (int)xc;
        int   x1c = min(x0 + 1, W_ - 1);
        float lx  = xc - (float)x0;
        xo[sx][0] = x0;
        xo[sx][1] = x1c;
        wx[sx][0] = (1.0f - lx) * vx;
        wx[sx][1] = lx * vx;
    }

    // Issue all 16 loads unguarded (all addresses in-bounds by construction).
    float v[2][2][2][2];
#pragma unroll
    for (int sy = 0; sy < 2; ++sy)
#pragma unroll
        for (int sx = 0; sx < 2; ++sx)
#pragma unroll
            for (int iy = 0; iy < 2; ++iy)
#pragma unroll
                for (int ix = 0; ix < 2; ++ix)
                    v[sy][sx][iy][ix] = fplane[ro[sy][iy] + xo[sx][ix]];

    float acc = 0.0f;
#pragma unroll
    for (int sy = 0; sy < 2; ++sy)
#pragma unroll
        for (int sx = 0; sx < 2; ++sx)
#pragma unroll
            for (int iy = 0; iy < 2; ++iy)
#pragma unroll
                for (int ix = 0; ix < 2; ++ix)
                    acc += wy[sy][iy] * wx[sx][ix] * v[sy][sx][iy][ix];

    int k  = c * 49 + bin;
    int kb = k >> 5;
    int kw = k & 31;
    featT[((size_t)kb * 64 + b) * 32 + kw] = f2bf(acc * 0.25f);
}

// ---------------------------------------------------------------------------
// Kernel 2: LDS-free bf16 MFMA GEMM with split-K, software-pipelined:
// next chunk's global loads issue before the current chunk's cvt+MFMA cluster.
//   h[b][r] = sum_k feat[b][k] * w[r][k]
// grid = (16 r-tiles of 64, KG_ k-groups); block = 256 = 4 waves.
// ---------------------------------------------------------------------------
__global__ __launch_bounds__(256) void gemm_mfma(const short* __restrict__ featT,
                                                 const float* __restrict__ fc_w,
                                                 float* __restrict__ hpart) {
    int lane = threadIdx.x & 63;
    int wv   = threadIdx.x >> 6;
    int m    = lane & 15;        // n index within tile (r), and b row for A
    int q    = lane >> 4;        // quad: k sub-block
    int r0   = blockIdx.x * 64 + wv * 16;
    int g    = blockIdx.y;

    const float* wrow  = fc_w + (size_t)(r0 + m) * K_ + q * 8;
    const short* afeat = featT + (size_t)m * 32 + q * 8;

    f32x4 acc0 = {0.f, 0.f, 0.f, 0.f};
    f32x4 acc1 = {0.f, 0.f, 0.f, 0.f};
    f32x4 acc2 = {0.f, 0.f, 0.f, 0.f};
    f32x4 acc3 = {0.f, 0.f, 0.f, 0.f};

    int kb = g;
    // prologue loads for chunk g
    f32x4 w0 = *reinterpret_cast<const f32x4*>(wrow + kb * 32);
    f32x4 w1 = *reinterpret_cast<const f32x4*>(wrow + kb * 32 + 4);
    short8 a0 = *reinterpret_cast<const short8*>(afeat + (size_t)kb * 2048);
    short8 a1 = *reinterpret_cast<const short8*>(afeat + (size_t)kb * 2048 + 512);
    short8 a2 = *reinterpret_cast<const short8*>(afeat + (size_t)kb * 2048 + 1024);
    short8 a3 = *reinterpret_cast<const short8*>(afeat + (size_t)kb * 2048 + 1536);

    for (;;) {
        int  kbn  = kb + KG_;
        bool more = kbn < KB_;

        f32x4 nw0, nw1;
        short8 na0, na1, na2, na3;
        if (more) {   // prefetch next chunk before current compute
            nw0 = *reinterpret_cast<const f32x4*>(wrow + kbn * 32);
            nw1 = *reinterpret_cast<const f32x4*>(wrow + kbn * 32 + 4);
            na0 = *reinterpret_cast<const short8*>(afeat + (size_t)kbn * 2048);
            na1 = *reinterpret_cast<const short8*>(afeat + (size_t)kbn * 2048 + 512);
            na2 = *reinterpret_cast<const short8*>(afeat + (size_t)kbn * 2048 + 1024);
            na3 = *reinterpret_cast<const short8*>(afeat + (size_t)kbn * 2048 + 1536);
        }

        short8 bfrag;
        bfrag[0] = f2bf(w0[0]); bfrag[1] = f2bf(w0[1]);
        bfrag[2] = f2bf(w0[2]); bfrag[3] = f2bf(w0[3]);
        bfrag[4] = f2bf(w1[0]); bfrag[5] = f2bf(w1[1]);
        bfrag[6] = f2bf(w1[2]); bfrag[7] = f2bf(w1[3]);

        acc0 = __builtin_amdgcn_mfma_f32_16x16x32_bf16(a0, bfrag, acc0, 0, 0, 0);
        acc1 = __builtin_amdgcn_mfma_f32_16x16x32_bf16(a1, bfrag, acc1, 0, 0, 0);
        acc2 = __builtin_amdgcn_mfma_f32_16x16x32_bf16(a2, bfrag, acc2, 0, 0, 0);
        acc3 = __builtin_amdgcn_mfma_f32_16x16x32_bf16(a3, bfrag, acc3, 0, 0, 0);

        if (!more) break;
        w0 = nw0; w1 = nw1;
        a0 = na0; a1 = na1; a2 = na2; a3 = na3;
        kb = kbn;
    }

    // C/D layout: r = r0 + (lane&15), b = mt*16 + quad*4 + reg
    float* hp = hpart + ((size_t)g * R_ + (r0 + m)) * 64 + q * 4;
#pragma unroll
    for (int i = 0; i < 4; ++i) hp[ 0 + i] = acc0[i];
#pragma unroll
    for (int i = 0; i < 4; ++i) hp[16 + i] = acc1[i];
#pragma unroll
    for (int i = 0; i < 4; ++i) hp[32 + i] = acc2[i];
#pragma unroll
    for (int i = 0; i < 4; ++i) hp[48 + i] = acc3[i];
}

// ---------------------------------------------------------------------------
// Kernel 3: reduce split-K partials, bias+ReLU, batch mean/var (wave=64=B),
// normalize, write out[b][r].  One wave per r.  grid = 256 blocks * 4 waves.
// ---------------------------------------------------------------------------
__global__ __launch_bounds__(256) void stats_kernel(const float* __restrict__ hpart,
                                                    const float* __restrict__ fc_b,
                                                    const float* __restrict__ gamma,
                                                    const float* __restrict__ beta,
                                                    float* __restrict__ out) {
    int wv   = threadIdx.x >> 6;
    int lane = threadIdx.x & 63;
    int r    = blockIdx.x * 4 + wv;

    float s = fc_b[r];
#pragma unroll
    for (int g = 0; g < KG_; ++g)
        s += hpart[((size_t)g * R_ + r) * 64 + lane];
    float h = fmaxf(s, 0.0f);

    float sum = h, sq = h * h;
#pragma unroll
    for (int off = 32; off >= 1; off >>= 1) {
        sum += __shfl_xor(sum, off);
        sq  += __shfl_xor(sq,  off);
    }
    float mu  = sum * (1.0f / 64.0f);
    float var = sq * (1.0f / 64.0f) - mu * mu;
    out[lane * R_ + r] = (h - mu) * rsqrtf(var + 1e-5f) * gamma[r] + beta[r];
}

extern "C" void kernel_launch(void* const* d_in, const int* in_sizes, int n_in,
                              void* d_out, int out_size, void* d_ws, size_t ws_size,
                              hipStream_t stream) {
    const float* x     = (const float*)d_in[0];
    const float* bbox  = (const float*)d_in[1];
    const float* fc_w  = (const float*)d_in[2];
    const float* fc_b  = (const float*)d_in[3];
    const float* gamma = (const float*)d_in[4];
    const float* beta  = (const float*)d_in[5];
    float* out = (float*)d_out;

    short* featT = (short*)d_ws;                                // K_*64 bf16 = 1.6 MB
    float* hpart = (float*)((char*)d_ws + (size_t)K_ * 64 * 2); // KG_*R_*64 f32 = 8 MB

    roi_kernel<<<dim3((B_ * K_) / 256), dim3(256), 0, stream>>>(x, bbox, featT);
    gemm_mfma<<<dim3(16, KG_), dim3(256), 0, stream>>>(featT, fc_w, hpart);
    stats_kernel<<<dim3(R_ / 4), dim3(256), 0, stream>>>(hpart, fc_b, gamma, beta, out);
}